// Round 9
// baseline (203.011 us; speedup 1.0000x reference)
//
#include <hip/hip_runtime.h>
#include <stdint.h>

#define BB 16
#define NN 25200
#define CC 85
#define NCLS 80
#define KK 1000
#define CAP 2048        // candidate pool per batch (top-k + pivot-bin ties)
#define NBIN 4096       // histogram bins over score bits (0.25,1.0]
#define BINBASE 0x3E800000u  // float bits of 0.25f
#define TILE 84         // rows per k_score block; 25200 = 84 * 300
#define NTILE 300
#define SBLK 384        // k_score block size (6 waves)
#define CONF 0.25f
#define IOUT 0.45f
#define MAXWH 4096.0f
#define NW 16           // 1000 bits -> 16 u64 words

typedef unsigned long long u64;
typedef unsigned int u32;

__device__ __forceinline__ u64 umax64(u64 a, u64 b) { return a > b ? a : b; }

// Monotone bin over valid scores (sb in (0x3E800000, 0x3F800000]).
__device__ __forceinline__ u32 score_bin(u32 sb) {
  u32 d = (sb - BINBASE) >> 12;
  return d > (NBIN - 1) ? (NBIN - 1) : d;
}

// ---- kernel 0: zero the histogram ----------------------------------------
__global__ __launch_bounds__(256) void k_zero(uint4* __restrict__ p, int n4) {
  int i = blockIdx.x * 256 + threadIdx.x;
  if (i < n4) p[i] = make_uint4(0u, 0u, 0u, 0u);
}

// ---- kernel 1: score + sortable key + per-batch histogram -----------------
// key = score_bits(32) | (~idx & 0xFFFF) << 16 | cls << 8
__global__ __launch_bounds__(SBLK) void k_score(const float* __restrict__ x,
                                                u64* __restrict__ keys,
                                                u32* __restrict__ hist) {
#pragma clang fp contract(off)
  __shared__ float tile[TILE * CC];  // 28560 B
  __shared__ u32 zc;
  int b = blockIdx.x / NTILE;
  int t = blockIdx.x % NTILE;
  int tid = threadIdx.x;
  int base_row = t * TILE;
  const float4* src4 =
      (const float4*)(x + ((size_t)b * NN + base_row) * CC);
  float4* tile4 = (float4*)tile;
  if (tid == 0) zc = 0;
#pragma unroll
  for (int i = tid; i < TILE * CC / 4; i += SBLK) tile4[i] = src4[i];
  __syncthreads();

  if (tid < TILE * 4) {
    int row = tid >> 2, r = tid & 3;
    const float* rp = tile + row * CC;
    float obj = rp[4];
    float best = -1.0f;
    int bj = 0;
#pragma unroll
    for (int c = 0; c < 20; ++c) {
      float p = obj * rp[5 + r * 20 + c];
      if (p > best) { best = p; bj = r * 20 + c; }
    }
    u64 ck = ((u64)__float_as_uint(best) << 32) | (u32)(~(u32)bj);
    ck = umax64(ck, __shfl_xor(ck, 1));
    ck = umax64(ck, __shfl_xor(ck, 2));
    if (r == 0) {
      float bestv = __uint_as_float((u32)(ck >> 32));
      u32 j = ~(u32)(ck & 0xFFFFFFFFu);
      bool valid = (obj > CONF) && (bestv > CONF);
      float score = valid ? bestv : 0.0f;
      u32 sb = __float_as_uint(score);
      int n = base_row + row;
      u64 key = ((u64)sb << 32) | ((u64)(~(u32)n & 0xFFFFu) << 16) |
                ((u64)(j & 0xFFu) << 8);
      keys[(size_t)b * NN + n] = key;
      if (sb) {
        atomicAdd(&hist[b * NBIN + score_bin(sb)], 1u);
      } else {
        atomicAdd(&zc, 1u);
      }
    }
  }
  __syncthreads();
  if (tid == 0 && zc) atomicAdd(&hist[b * NBIN + 0], zc);
}

// ---- kernel 2 (fused): pivot + compact + bitonic sort + gather ------------
__global__ __launch_bounds__(1024) void k_sel2(const float* __restrict__ x,
                                               const u64* __restrict__ keys,
                                               const u32* __restrict__ hist,
                                               float* __restrict__ out,
                                               float* __restrict__ offbox,
                                               float* __restrict__ areas,
                                               float* __restrict__ vals) {
#pragma clang fp contract(off)
  __shared__ u32 s[1024];   // 4 KB (pivot scan)
  __shared__ u64 buf[CAP];  // 16 KB (candidates -> sorted keys)
  __shared__ u32 s_pivot, scnt;
  int b = blockIdx.x, tid = threadIdx.x;

  // --- pivot: suffix-scan the 4096-bin histogram, find rank-KK bin ---
  const uint4* h4 = (const uint4*)(hist + b * NBIN);
  uint4 v = h4[tid];  // bins [tid*4, tid*4+4)
  u32 c = v.x + v.y + v.z + v.w;
  s[tid] = c;
  if (tid == 0) scnt = 0;
  __syncthreads();
  u32 inc = c;
  for (int off = 1; off < 1024; off <<= 1) {
    u32 add = (tid + off < 1024) ? s[tid + off] : 0u;
    __syncthreads();
    inc += add;
    s[tid] = inc;
    __syncthreads();
  }
  if (inc >= KK && inc - c < KK) {  // unique thread (needs c>0)
    u32 cum = inc - c;
    u32 hv[4] = {v.x, v.y, v.z, v.w};
    for (int i = 3; i >= 0; --i) {
      u32 hh = hv[i];
      if (cum + hh >= KK) { s_pivot = (u32)(tid * 4 + i); break; }
      cum += hh;
    }
  }
  buf[tid] = 0ULL;
  buf[tid + 1024] = 0ULL;
  __syncthreads();
  u32 pivot = s_pivot;

  // --- compact: scan this batch's keys, wave-aggregated append into LDS ---
  const u64* kb = keys + (size_t)b * NN;
  int lane = tid & 63;
  for (int base = 0; base < NN; base += 1024) {
    int n = base + tid;
    bool cond = false;
    u64 key = 0;
    if (n < NN) {
      key = kb[n];
      u32 sb = (u32)(key >> 32);
      cond = sb && (score_bin(sb) >= pivot);
    }
    u64 m = __ballot(cond);
    if (m) {
      int leader = (int)__ffsll((long long)m) - 1;
      u32 tot = (u32)__popcll(m);
      u32 wbase = 0;
      if (lane == leader) wbase = atomicAdd(&scnt, tot);
      wbase = (u32)__shfl((int)wbase, leader);
      if (cond) {
        u32 pos = wbase + (u32)__popcll(m & ((1ULL << lane) - 1ULL));
        if (pos < CAP) buf[pos] = key;
      }
    }
  }
  __syncthreads();

  // --- bitonic sort, descending, 2048 elems / 1024 threads ---
  for (int k2 = 2; k2 <= CAP; k2 <<= 1) {
    for (int j = k2 >> 1; j > 0; j >>= 1) {
      for (int i = tid; i < CAP; i += 1024) {
        int ixj = i ^ j;
        if (ixj > i) {
          u64 a = buf[i], cc = buf[ixj];
          bool up = (i & k2) == 0;  // descending overall
          bool sw = up ? (a < cc) : (a > cc);
          if (sw) { buf[i] = cc; buf[ixj] = a; }
        }
      }
      __syncthreads();
    }
  }

  // --- gather: boxes/cls -> out ; offbox/areas/vals -> ws ---
  if (tid < KK) {
    u64 key = buf[tid];
    u32 ni = 65535u - (u32)((key >> 16) & 0xFFFFu);
    if (ni > NN - 1) ni = NN - 1;  // guard (unreachable for this data)
    u32 j = (u32)((key >> 8) & 0xFFu);
    float val = __uint_as_float((u32)(key >> 32));
    const float* row = x + ((size_t)b * NN + ni) * CC;
    float cx = row[0], cy = row[1], w = row[2], h = row[3];
    float x1 = cx - w * 0.5f, y1 = cy - h * 0.5f;
    float x2 = cx + w * 0.5f, y2 = cy + h * 0.5f;
    float cls = (float)j;
    float off = cls * MAXWH;
    float* o = out + ((size_t)b * KK + tid) * 6;
    o[0] = x1; o[1] = y1; o[2] = x2; o[3] = y2; o[5] = cls;
    float* ob = offbox + ((size_t)b * KK + tid) * 4;
    float ox1 = x1 + off, oy1 = y1 + off, ox2 = x2 + off, oy2 = y2 + off;
    ob[0] = ox1; ob[1] = oy1; ob[2] = ox2; ob[3] = oy2;
    areas[(size_t)b * KK + tid] = (ox2 - ox1) * (oy2 - oy1);
    vals[(size_t)b * KK + tid] = val;
  }
}

// ---- kernel 3: suppression bitmask ----------------------------------------
__global__ void k_mask(const float* __restrict__ offbox,
                       const float* __restrict__ areas,
                       u64* __restrict__ mask) {
#pragma clang fp contract(off)
  int t = threadIdx.x;
  int w = t & 15;
  int r = t >> 4;
  int blk = blockIdx.x;
  int b = blk / 63;
  int i = (blk % 63) * 16 + r;
  if (i >= KK) return;
  const float4* ob4 = (const float4*)(offbox + (size_t)b * KK * 4);
  const float* ar = areas + (size_t)b * KK;
  float4 A = ob4[i];
  float aa = ar[i];
  u64 bits = 0ULL;
  int j0 = w * 64;
  for (int jj = 0; jj < 64; ++jj) {
    int j = j0 + jj;
    if (j >= KK) break;
    if (j <= i) continue;
    float4 Bx = ob4[j];
    float lx = fmaxf(A.x, Bx.x), ly = fmaxf(A.y, Bx.y);
    float rx = fminf(A.z, Bx.z), ry = fminf(A.w, Bx.w);
    float ww = rx - lx; ww = ww > 0.0f ? ww : 0.0f;
    float hh = ry - ly; hh = hh > 0.0f ? hh : 0.0f;
    float inter = ww * hh;
    float iou = inter / (aa + ar[j] - inter + 1e-7f);
    if (iou > IOUT) bits |= (1ULL << jj);
  }
  mask[((size_t)b * KK + i) * NW + w] = bits;
}

// ---- kernel 4: serial greedy scan + final score ---------------------------
__global__ __launch_bounds__(64) void k_scan(const u64* __restrict__ mask,
                                             const float* __restrict__ vals,
                                             float* __restrict__ out) {
  int b = blockIdx.x;
  int lane = threadIdx.x;
  const u64* mb = mask + (size_t)b * KK * NW;
  int w = lane & 15;
  u64 keep = ~0ULL;
  __shared__ u64 skeep[NW];

  u64 r0 = mb[(size_t)0 * NW + w];
  u64 r1 = mb[(size_t)1 * NW + w];
  u64 r2 = mb[(size_t)2 * NW + w];
  u64 r3 = mb[(size_t)3 * NW + w];

#define STEP(I, RV)                                                        \
  {                                                                        \
    int i_ = (I);                                                          \
    int wi_ = i_ >> 6;                                                     \
    u32 half_ = (i_ & 32) ? (u32)(keep >> 32) : (u32)keep;                 \
    u32 kw_ = (u32)__builtin_amdgcn_readlane((int)half_, wi_);             \
    u32 bit_ = (kw_ >> (i_ & 31)) & 1u;                                    \
    keep &= bit_ ? ~RV : ~0ULL;                                            \
  }

  for (int base = 0; base < KK; base += 4) {
    int p0 = base + 4 < KK ? base + 4 : KK - 1;
    int p1 = base + 5 < KK ? base + 5 : KK - 1;
    int p2 = base + 6 < KK ? base + 6 : KK - 1;
    int p3 = base + 7 < KK ? base + 7 : KK - 1;
    u64 n0 = mb[(size_t)p0 * NW + w];
    u64 n1 = mb[(size_t)p1 * NW + w];
    u64 n2 = mb[(size_t)p2 * NW + w];
    u64 n3 = mb[(size_t)p3 * NW + w];
    STEP(base + 0, r0)
    STEP(base + 1, r1)
    STEP(base + 2, r2)
    STEP(base + 3, r3)
    r0 = n0; r1 = n1; r2 = n2; r3 = n3;
  }
#undef STEP

  if (lane < NW) skeep[lane] = keep;
  __syncthreads();
  for (int s = lane; s < KK; s += 64) {
    float v = vals[(size_t)b * KK + s];
    u64 kwv = skeep[s >> 6];
    float kbit = (float)((kwv >> (s & 63)) & 1ULL);
    float fs = v * kbit * (v > CONF ? 1.0f : 0.0f);
    out[((size_t)b * KK + s) * 6 + 4] = fs;
  }
}

extern "C" void kernel_launch(void* const* d_in, const int* in_sizes, int n_in,
                              void* d_out, int out_size, void* d_ws,
                              size_t ws_size, hipStream_t stream) {
  const float* x = (const float*)d_in[0];
  float* out = (float*)d_out;
  char* ws = (char*)d_ws;
  (void)in_sizes; (void)n_in; (void)out_size; (void)ws_size;

  auto align256 = [](size_t v) { return (v + 255) & ~(size_t)255; };
  size_t keys_off = 0;
  size_t keys_sz = (size_t)BB * NN * 8;                 // 3.226 MB
  size_t hist_off = align256(keys_off + keys_sz);
  size_t hist_sz = (size_t)BB * NBIN * 4;               // 256 KB
  size_t offbox_off = align256(hist_off + hist_sz);
  size_t offbox_sz = (size_t)BB * KK * 4 * 4;           // 256 KB
  size_t areas_off = align256(offbox_off + offbox_sz);
  size_t areas_sz = (size_t)BB * KK * 4;
  size_t vals_off = align256(areas_off + areas_sz);
  size_t mask_off = keys_off;  // alias: keys dead after k_sel2

  u64* keys = (u64*)(ws + keys_off);
  u32* hist = (u32*)(ws + hist_off);
  float* offbox = (float*)(ws + offbox_off);
  float* areas = (float*)(ws + areas_off);
  float* vals = (float*)(ws + vals_off);
  u64* mask = (u64*)(ws + mask_off);

  int n4 = (int)(hist_sz / 16);
  k_zero<<<dim3((n4 + 255) / 256), dim3(256), 0, stream>>>(
      (uint4*)(ws + hist_off), n4);
  k_score<<<dim3(BB * NTILE), dim3(SBLK), 0, stream>>>(x, keys, hist);
  k_sel2<<<dim3(BB), dim3(1024), 0, stream>>>(x, keys, hist, out, offbox,
                                              areas, vals);
  k_mask<<<dim3(BB * 63), dim3(256), 0, stream>>>(offbox, areas, mask);
  k_scan<<<dim3(BB), dim3(64), 0, stream>>>(mask, vals, out);
}

// Round 10
// 173.596 us; speedup vs baseline: 1.1694x; 1.1694x over previous
//
#include <hip/hip_runtime.h>
#include <stdint.h>

#define BB 16
#define NN 25200
#define CC 85
#define NCLS 80
#define KK 1000
#define CAP 2048        // candidate pool per batch (top-k + pivot-bin ties)
#define NBIN 4096       // histogram bins over score bits (0.25,1.0]
#define BINBASE 0x3E800000u  // float bits of 0.25f
#define TILE 84         // rows per k_score block; 25200 = 84 * 300
#define NTILE 300
#define SBLK 384        // k_score block size (6 waves)
#define CONF 0.25f
#define IOUT 0.45f
#define MAXWH 4096.0f
#define NW 16           // 1000 bits -> 16 u64 words

typedef unsigned long long u64;
typedef unsigned int u32;

__device__ __forceinline__ u64 umax64(u64 a, u64 b) { return a > b ? a : b; }

// Monotone bin over valid scores (sb in (0x3E800000, 0x3F800000]).
__device__ __forceinline__ u32 score_bin(u32 sb) {
  u32 d = (sb - BINBASE) >> 12;
  return d > (NBIN - 1) ? (NBIN - 1) : d;
}

// One bitonic compare-exchange step done in registers via shfl_xor.
// i = element index, j = partner distance (<64), k2 = bitonic block size.
__device__ __forceinline__ u64 regphase(u64 v, u32 i, int j, int k2) {
  u64 p = __shfl_xor(v, j);
  bool lower = (i & (u32)j) == 0;
  bool desc = (i & (u32)k2) == 0;
  bool keepmax = (desc == lower);
  u64 mx = v > p ? v : p;
  u64 mn = v > p ? p : v;
  return keepmax ? mx : mn;
}

// ---- kernel 0: zero the histogram ----------------------------------------
__global__ __launch_bounds__(256) void k_zero(uint4* __restrict__ p, int n4) {
  int i = blockIdx.x * 256 + threadIdx.x;
  if (i < n4) p[i] = make_uint4(0u, 0u, 0u, 0u);
}

// ---- kernel 1: score + sortable key + per-batch histogram -----------------
// key = score_bits(32) | (~idx & 0xFFFF) << 16 | cls << 8
__global__ __launch_bounds__(SBLK) void k_score(const float* __restrict__ x,
                                                u64* __restrict__ keys,
                                                u32* __restrict__ hist) {
#pragma clang fp contract(off)
  __shared__ float tile[TILE * CC];  // 28560 B
  __shared__ u32 zc;
  int b = blockIdx.x / NTILE;
  int t = blockIdx.x % NTILE;
  int tid = threadIdx.x;
  int base_row = t * TILE;
  const float4* src4 =
      (const float4*)(x + ((size_t)b * NN + base_row) * CC);
  float4* tile4 = (float4*)tile;
  if (tid == 0) zc = 0;
#pragma unroll
  for (int i = tid; i < TILE * CC / 4; i += SBLK) tile4[i] = src4[i];
  __syncthreads();

  if (tid < TILE * 4) {
    int row = tid >> 2, r = tid & 3;
    const float* rp = tile + row * CC;
    float obj = rp[4];
    float best = -1.0f;
    int bj = 0;
#pragma unroll
    for (int c = 0; c < 20; ++c) {
      float p = obj * rp[5 + r * 20 + c];
      if (p > best) { best = p; bj = r * 20 + c; }
    }
    u64 ck = ((u64)__float_as_uint(best) << 32) | (u32)(~(u32)bj);
    ck = umax64(ck, __shfl_xor(ck, 1));
    ck = umax64(ck, __shfl_xor(ck, 2));
    if (r == 0) {
      float bestv = __uint_as_float((u32)(ck >> 32));
      u32 j = ~(u32)(ck & 0xFFFFFFFFu);
      bool valid = (obj > CONF) && (bestv > CONF);
      float score = valid ? bestv : 0.0f;
      u32 sb = __float_as_uint(score);
      int n = base_row + row;
      u64 key = ((u64)sb << 32) | ((u64)(~(u32)n & 0xFFFFu) << 16) |
                ((u64)(j & 0xFFu) << 8);
      keys[(size_t)b * NN + n] = key;
      if (sb) {
        atomicAdd(&hist[b * NBIN + score_bin(sb)], 1u);
      } else {
        atomicAdd(&zc, 1u);
      }
    }
  }
  __syncthreads();
  if (tid == 0 && zc) atomicAdd(&hist[b * NBIN + 0], zc);
}

// ---- kernel 2 (fused): pivot + compact + hybrid bitonic sort + gather -----
__global__ __launch_bounds__(1024) void k_sel2(const float* __restrict__ x,
                                               const u64* __restrict__ keys,
                                               const u32* __restrict__ hist,
                                               float* __restrict__ out,
                                               float* __restrict__ offbox,
                                               float* __restrict__ areas,
                                               float* __restrict__ vals) {
#pragma clang fp contract(off)
  __shared__ u32 s[1024];   // 4 KB (pivot scan)
  __shared__ u64 buf[CAP];  // 16 KB (candidates -> sorted keys)
  __shared__ u32 s_pivot, scnt;
  int b = blockIdx.x, tid = threadIdx.x;

  // --- pivot: suffix-scan the 4096-bin histogram, find rank-KK bin ---
  const uint4* h4 = (const uint4*)(hist + b * NBIN);
  uint4 v = h4[tid];  // bins [tid*4, tid*4+4)
  u32 c = v.x + v.y + v.z + v.w;
  s[tid] = c;
  if (tid == 0) scnt = 0;
  __syncthreads();
  u32 inc = c;
  for (int off = 1; off < 1024; off <<= 1) {
    u32 add = (tid + off < 1024) ? s[tid + off] : 0u;
    __syncthreads();
    inc += add;
    s[tid] = inc;
    __syncthreads();
  }
  if (inc >= KK && inc - c < KK) {  // unique thread (needs c>0)
    u32 cum = inc - c;
    u32 hv[4] = {v.x, v.y, v.z, v.w};
    for (int i = 3; i >= 0; --i) {
      u32 hh = hv[i];
      if (cum + hh >= KK) { s_pivot = (u32)(tid * 4 + i); break; }
      cum += hh;
    }
  }
  buf[tid] = 0ULL;
  buf[tid + 1024] = 0ULL;
  __syncthreads();
  u32 pivot = s_pivot;

  // --- compact: wave-aggregated append into LDS, 1-deep load pipeline ---
  const u64* kb = keys + (size_t)b * NN;
  int lane = tid & 63;
  u64 key = (tid < NN) ? kb[tid] : 0ULL;
  for (int base = 0; base < NN; base += 1024) {
    int n2 = base + 1024 + tid;
    u64 nxt = (n2 < NN) ? kb[n2] : 0ULL;
    int n = base + tid;
    u32 sb = (u32)(key >> 32);
    bool cond = (n < NN) && sb && (score_bin(sb) >= pivot);
    u64 m = __ballot(cond);
    if (m) {
      int leader = (int)__ffsll((long long)m) - 1;
      u32 tot = (u32)__popcll(m);
      u32 wbase = 0;
      if (lane == leader) wbase = atomicAdd(&scnt, tot);
      wbase = (u32)__shfl((int)wbase, leader);
      if (cond) {
        u32 pos = wbase + (u32)__popcll(m & ((1ULL << lane) - 1ULL));
        if (pos < CAP) buf[pos] = key;
      }
    }
    key = nxt;
  }
  __syncthreads();

  // --- hybrid bitonic sort, descending, 2048 elems ---
  // j<64 phases in registers (shfl_xor, in-wave partners); j>=64 in LDS.
  u64 A = buf[tid], B = buf[tid + 1024];
#pragma unroll
  for (int k2 = 2; k2 <= 64; k2 <<= 1) {
#pragma unroll
    for (int j = k2 >> 1; j >= 1; j >>= 1) {
      A = regphase(A, (u32)tid, j, k2);
      B = regphase(B, (u32)(tid + 1024), j, k2);
    }
  }
  buf[tid] = A; buf[tid + 1024] = B;
  __syncthreads();
  for (int k2 = 128; k2 <= CAP; k2 <<= 1) {
    for (int j = k2 >> 1; j >= 64; j >>= 1) {
#pragma unroll
      for (int e = 0; e < 2; ++e) {
        int i = tid + e * 1024;
        int ixj = i ^ j;
        if (ixj > i) {
          u64 a = buf[i], cc = buf[ixj];
          bool up = (i & k2) == 0;
          bool sw = up ? (a < cc) : (a > cc);
          if (sw) { buf[i] = cc; buf[ixj] = a; }
        }
      }
      __syncthreads();
    }
    A = buf[tid]; B = buf[tid + 1024];
#pragma unroll
    for (int j = 32; j >= 1; j >>= 1) {
      A = regphase(A, (u32)tid, j, k2);
      B = regphase(B, (u32)(tid + 1024), j, k2);
    }
    buf[tid] = A; buf[tid + 1024] = B;
    __syncthreads();
  }

  // --- gather: boxes/cls -> out ; offbox/areas/vals -> ws ---
  if (tid < KK) {
    u64 kk = buf[tid];
    u32 ni = 65535u - (u32)((kk >> 16) & 0xFFFFu);
    if (ni > NN - 1) ni = NN - 1;  // guard (unreachable for this data)
    u32 j = (u32)((kk >> 8) & 0xFFu);
    float val = __uint_as_float((u32)(kk >> 32));
    const float* row = x + ((size_t)b * NN + ni) * CC;
    float cx = row[0], cy = row[1], w = row[2], h = row[3];
    float x1 = cx - w * 0.5f, y1 = cy - h * 0.5f;
    float x2 = cx + w * 0.5f, y2 = cy + h * 0.5f;
    float cls = (float)j;
    float off = cls * MAXWH;
    float* o = out + ((size_t)b * KK + tid) * 6;
    o[0] = x1; o[1] = y1; o[2] = x2; o[3] = y2; o[5] = cls;
    float* ob = offbox + ((size_t)b * KK + tid) * 4;
    float ox1 = x1 + off, oy1 = y1 + off, ox2 = x2 + off, oy2 = y2 + off;
    ob[0] = ox1; ob[1] = oy1; ob[2] = ox2; ob[3] = oy2;
    areas[(size_t)b * KK + tid] = (ox2 - ox1) * (oy2 - oy1);
    vals[(size_t)b * KK + tid] = val;
  }
}

// ---- kernel 3: suppression bitmask ----------------------------------------
__global__ void k_mask(const float* __restrict__ offbox,
                       const float* __restrict__ areas,
                       u64* __restrict__ mask) {
#pragma clang fp contract(off)
  int t = threadIdx.x;
  int w = t & 15;
  int r = t >> 4;
  int blk = blockIdx.x;
  int b = blk / 63;
  int i = (blk % 63) * 16 + r;
  if (i >= KK) return;
  const float4* ob4 = (const float4*)(offbox + (size_t)b * KK * 4);
  const float* ar = areas + (size_t)b * KK;
  float4 A = ob4[i];
  float aa = ar[i];
  u64 bits = 0ULL;
  int j0 = w * 64;
  for (int jj = 0; jj < 64; ++jj) {
    int j = j0 + jj;
    if (j >= KK) break;
    if (j <= i) continue;
    float4 Bx = ob4[j];
    float lx = fmaxf(A.x, Bx.x), ly = fmaxf(A.y, Bx.y);
    float rx = fminf(A.z, Bx.z), ry = fminf(A.w, Bx.w);
    float ww = rx - lx; ww = ww > 0.0f ? ww : 0.0f;
    float hh = ry - ly; hh = hh > 0.0f ? hh : 0.0f;
    float inter = ww * hh;
    float iou = inter / (aa + ar[j] - inter + 1e-7f);
    if (iou > IOUT) bits |= (1ULL << jj);
  }
  mask[((size_t)b * KK + i) * NW + w] = bits;
}

// ---- kernel 4: serial greedy scan + final score ---------------------------
// 16-row double-buffered prefetch: loads issued a full chunk (~16 steps)
// ahead of use, covering L2 latency.
__global__ __launch_bounds__(64) void k_scan(const u64* __restrict__ mask,
                                             const float* __restrict__ vals,
                                             float* __restrict__ out) {
  int b = blockIdx.x;
  int lane = threadIdx.x;
  const u64* mb = mask + (size_t)b * KK * NW;
  int w = lane & 15;
  u64 keep = ~0ULL;
  __shared__ u64 skeep[NW];

  u64 a[16], nb[16];
#pragma unroll
  for (int s2 = 0; s2 < 16; ++s2) a[s2] = mb[(size_t)s2 * NW + w];

  for (int base = 0; base < KK; base += 16) {
#pragma unroll
    for (int s2 = 0; s2 < 16; ++s2) {
      int pr = base + 16 + s2;
      if (pr > KK - 1) pr = KK - 1;
      nb[s2] = mb[(size_t)pr * NW + w];
    }
#pragma unroll
    for (int s2 = 0; s2 < 16; ++s2) {
      int i_ = base + s2;
      int wi_ = i_ >> 6;
      u32 half_ = (i_ & 32) ? (u32)(keep >> 32) : (u32)keep;
      u32 kw_ = (u32)__builtin_amdgcn_readlane((int)half_, wi_);
      u32 bit_ = (kw_ >> (i_ & 31)) & 1u;
      if (i_ >= KK) bit_ = 0;
      keep &= bit_ ? ~a[s2] : ~0ULL;
    }
#pragma unroll
    for (int s2 = 0; s2 < 16; ++s2) a[s2] = nb[s2];
  }

  if (lane < NW) skeep[lane] = keep;
  __syncthreads();
  for (int s2 = lane; s2 < KK; s2 += 64) {
    float v = vals[(size_t)b * KK + s2];
    u64 kwv = skeep[s2 >> 6];
    float kbit = (float)((kwv >> (s2 & 63)) & 1ULL);
    float fs = v * kbit * (v > CONF ? 1.0f : 0.0f);
    out[((size_t)b * KK + s2) * 6 + 4] = fs;
  }
}

extern "C" void kernel_launch(void* const* d_in, const int* in_sizes, int n_in,
                              void* d_out, int out_size, void* d_ws,
                              size_t ws_size, hipStream_t stream) {
  const float* x = (const float*)d_in[0];
  float* out = (float*)d_out;
  char* ws = (char*)d_ws;
  (void)in_sizes; (void)n_in; (void)out_size; (void)ws_size;

  auto align256 = [](size_t v) { return (v + 255) & ~(size_t)255; };
  size_t keys_off = 0;
  size_t keys_sz = (size_t)BB * NN * 8;                 // 3.226 MB
  size_t hist_off = align256(keys_off + keys_sz);
  size_t hist_sz = (size_t)BB * NBIN * 4;               // 256 KB
  size_t offbox_off = align256(hist_off + hist_sz);
  size_t offbox_sz = (size_t)BB * KK * 4 * 4;           // 256 KB
  size_t areas_off = align256(offbox_off + offbox_sz);
  size_t areas_sz = (size_t)BB * KK * 4;
  size_t vals_off = align256(areas_off + areas_sz);
  size_t mask_off = keys_off;  // alias: keys dead after k_sel2

  u64* keys = (u64*)(ws + keys_off);
  u32* hist = (u32*)(ws + hist_off);
  float* offbox = (float*)(ws + offbox_off);
  float* areas = (float*)(ws + areas_off);
  float* vals = (float*)(ws + vals_off);
  u64* mask = (u64*)(ws + mask_off);

  int n4 = (int)(hist_sz / 16);
  k_zero<<<dim3((n4 + 255) / 256), dim3(256), 0, stream>>>(
      (uint4*)(ws + hist_off), n4);
  k_score<<<dim3(BB * NTILE), dim3(SBLK), 0, stream>>>(x, keys, hist);
  k_sel2<<<dim3(BB), dim3(1024), 0, stream>>>(x, keys, hist, out, offbox,
                                              areas, vals);
  k_mask<<<dim3(BB * 63), dim3(256), 0, stream>>>(offbox, areas, mask);
  k_scan<<<dim3(BB), dim3(64), 0, stream>>>(mask, vals, out);
}